// Round 2
// baseline (2153.859 us; speedup 1.0000x reference)
//
#include <hip/hip_runtime.h>
#include <math.h>

// Problem constants
#define B_ 32
#define D_ 192
#define DEPTH_ 4
#define DI_ 384
#define DS_ 16
#define DC_ 4
#define P_ 16
#define IMG_ 224
#define N_ 196
#define L_ 197

__device__ __forceinline__ float sigmoidf_(float x) { return 1.f / (1.f + expf(-x)); }

// ---------------- cls token + pos embed (row l=0) ----------------
__global__ void k_cls(const float* __restrict__ cls_tok, const float* __restrict__ pos,
                      float* __restrict__ t) {
  int b = blockIdx.x, d = threadIdx.x;
  t[(size_t)b * L_ * D_ + d] = cls_tok[d] + pos[d];
}

// ---------------- patch embed GEMM: tiles of 16 tokens, 2D reg blocking ----------------
// A-tile (16 tok x 768) in LDS, wave-uniform m-group -> broadcast ds_read_b128.
// Each thread: 4 tokens x 3 dims. W rows stream from global (L1/L2 resident).
__global__ __launch_bounds__(256) void k_patch(const float* __restrict__ x,
                                               const float* __restrict__ pw,
                                               const float* __restrict__ pb,
                                               const float* __restrict__ pos,
                                               float* __restrict__ t) {
  __shared__ __align__(16) float a_s[16 * 772];
  int tile = blockIdx.x, tid = threadIdx.x;
  int t0 = tile * 16;
  // stage 16 tokens x 768 features (im2col gather), float4 loads
#pragma unroll
  for (int jj = 0; jj < 12; jj++) {
    int idx = tid + jj * 256;       // float4 index 0..3071 (192 per token)
    int m = idx / 192;
    int q = idx - m * 192;          // f4 within token
    int tg = t0 + m;
    int b = tg / 196, p = tg - b * 196;
    int h = p / 14, wc = p - h * 14;
    int c = q >> 6;                 // channel (64 f4 each)
    int r = q & 63;
    int i = r >> 2;                 // row within patch
    int jl = (r & 3) << 2;          // float offset within 16-wide row
    float4 v = *(const float4*)(x + (((size_t)(b * 3 + c) * 224 + h * 16 + i) * 224 + wc * 16 + jl));
    *(float4*)(a_s + m * 772 + q * 4) = v;
  }
  __syncthreads();
  int mg = tid >> 6;                // wave-uniform: tokens mg*4..mg*4+3
  int ng = tid & 63;
  float acc[4][3];
#pragma unroll
  for (int i = 0; i < 4; i++)
#pragma unroll
    for (int j = 0; j < 3; j++) acc[i][j] = 0.f;
  const float* w0 = pw + (size_t)ng * 768;
  const float* w1 = pw + (size_t)(ng + 64) * 768;
  const float* w2 = pw + (size_t)(ng + 128) * 768;
  const float* a0 = a_s + (mg * 4 + 0) * 772;
  const float* a1 = a_s + (mg * 4 + 1) * 772;
  const float* a2 = a_s + (mg * 4 + 2) * 772;
  const float* a3 = a_s + (mg * 4 + 3) * 772;
  for (int k = 0; k < 768; k += 4) {
    float4 wv0 = *(const float4*)(w0 + k);
    float4 wv1 = *(const float4*)(w1 + k);
    float4 wv2 = *(const float4*)(w2 + k);
    float4 av0 = *(const float4*)(a0 + k);
    float4 av1 = *(const float4*)(a1 + k);
    float4 av2 = *(const float4*)(a2 + k);
    float4 av3 = *(const float4*)(a3 + k);
#define FMA4(ACC, AV, WV) \
    ACC = fmaf(AV.x, WV.x, fmaf(AV.y, WV.y, fmaf(AV.z, WV.z, fmaf(AV.w, WV.w, ACC))))
    FMA4(acc[0][0], av0, wv0); FMA4(acc[0][1], av0, wv1); FMA4(acc[0][2], av0, wv2);
    FMA4(acc[1][0], av1, wv0); FMA4(acc[1][1], av1, wv1); FMA4(acc[1][2], av1, wv2);
    FMA4(acc[2][0], av2, wv0); FMA4(acc[2][1], av2, wv1); FMA4(acc[2][2], av2, wv2);
    FMA4(acc[3][0], av3, wv0); FMA4(acc[3][1], av3, wv1); FMA4(acc[3][2], av3, wv2);
  }
#pragma unroll
  for (int i = 0; i < 4; i++) {
    int tg = t0 + mg * 4 + i;
    int b = tg / 196, p = tg - b * 196;
#pragma unroll
    for (int j = 0; j < 3; j++) {
      int n = ng + 64 * j;
      t[((size_t)b * L_ + 1 + p) * D_ + n] = acc[i][j] + pb[n] + pos[(size_t)(1 + p) * D_ + n];
    }
  }
}

// ---------------- fused LayerNorm + xz = ln(t) @ w_in^T ----------------
// grid = 394 tiles x 2 N-halves. Tile = 16 tokens. LN done in LDS, then GEMM
// with wave-uniform m-group (broadcast A reads) and 4m x 6n register tile.
__global__ __launch_bounds__(256) void k_ln_gemm_in(const float* __restrict__ t,
                                                    const float* __restrict__ g,
                                                    const float* __restrict__ bb,
                                                    const float* __restrict__ w,
                                                    float* __restrict__ xz) {
  __shared__ __align__(16) float a_s[16 * 196];
  int bx = blockIdx.x;
  int tile = bx >> 1, half = bx & 1;
  int tid = threadIdx.x;
  const float* ar = t + (size_t)tile * 16 * 192;
#pragma unroll
  for (int jj = 0; jj < 3; jj++) {
    int idx = tid + jj * 256;       // f4 index 0..767 (48 per token)
    int m = idx / 48;
    int q = idx - m * 48;
    float4 v = *(const float4*)(ar + m * 192 + q * 4);
    *(float4*)(a_s + m * 196 + q * 4) = v;
  }
  __syncthreads();
  // LN: 16 threads per token, 12 elems each
  {
    int m = tid >> 4, l16 = tid & 15;
    float vals[12];
    float s = 0.f, q = 0.f;
#pragma unroll
    for (int j = 0; j < 12; j++) {
      float v = a_s[m * 196 + l16 + 16 * j];
      vals[j] = v; s += v; q += v * v;
    }
#pragma unroll
    for (int off = 1; off < 16; off <<= 1) {
      s += __shfl_xor(s, off, 16);
      q += __shfl_xor(q, off, 16);
    }
    float mean = s * (1.f / 192.f);
    float r = rsqrtf(q * (1.f / 192.f) - mean * mean + 1e-5f);
#pragma unroll
    for (int j = 0; j < 12; j++) {
      int k = l16 + 16 * j;
      a_s[m * 196 + k] = (vals[j] - mean) * r * g[k] + bb[k];
    }
  }
  __syncthreads();
  int mg = tid >> 6;
  int ng = tid & 63;
  float acc[4][6];
#pragma unroll
  for (int i = 0; i < 4; i++)
#pragma unroll
    for (int j = 0; j < 6; j++) acc[i][j] = 0.f;
  const float* wr[6];
#pragma unroll
  for (int j = 0; j < 6; j++) wr[j] = w + (size_t)(half * 384 + ng + 64 * j) * 192;
  const float* a0 = a_s + (mg * 4 + 0) * 196;
  const float* a1 = a_s + (mg * 4 + 1) * 196;
  const float* a2 = a_s + (mg * 4 + 2) * 196;
  const float* a3 = a_s + (mg * 4 + 3) * 196;
  for (int k = 0; k < 192; k += 4) {
    float4 av0 = *(const float4*)(a0 + k);
    float4 av1 = *(const float4*)(a1 + k);
    float4 av2 = *(const float4*)(a2 + k);
    float4 av3 = *(const float4*)(a3 + k);
#pragma unroll
    for (int j = 0; j < 6; j++) {
      float4 wv = *(const float4*)(wr[j] + k);
      FMA4(acc[0][j], av0, wv);
      FMA4(acc[1][j], av1, wv);
      FMA4(acc[2][j], av2, wv);
      FMA4(acc[3][j], av3, wv);
    }
  }
#pragma unroll
  for (int i = 0; i < 4; i++) {
    size_t row = (size_t)tile * 16 + mg * 4 + i;
#pragma unroll
    for (int j = 0; j < 6; j++) {
      xz[row * 768 + half * 384 + ng + 64 * j] = acc[i][j];
    }
  }
}

// ---------------- causal depthwise conv (DC=4) + silu -> xa ; silu(z) -> sz ----------------
__global__ __launch_bounds__(384) void k_conv(const float* __restrict__ xz,
                                              const float* __restrict__ cw_,
                                              const float* __restrict__ cb,
                                              float* __restrict__ xa,
                                              float* __restrict__ sz) {
  int row = blockIdx.x;  // b*L + l
  int l = row % L_;
  int d = threadIdx.x;
  float4 cw = *(const float4*)(cw_ + d * 4);
  const float* xc = xz + (size_t)row * 768 + d;
  float acc = cb[d];
  acc = fmaf(cw.w, xc[0], acc);
  if (l >= 1) acc = fmaf(cw.z, xc[-768], acc);
  if (l >= 2) acc = fmaf(cw.y, xc[-2 * 768], acc);
  if (l >= 3) acc = fmaf(cw.x, xc[-3 * 768], acc);
  xa[(size_t)row * DI_ + d] = acc * sigmoidf_(acc);
  float z = xc[384];
  sz[(size_t)row * DI_ + d] = z * sigmoidf_(z);
}

// ---------------- bcd = xa @ w_x^T (N=33) ; fused dt = softplus(bcd[32]*w_dt+b_dt) ----------------
__global__ __launch_bounds__(256) void k_bcd(const float* __restrict__ xa,
                                             const float* __restrict__ w_x,
                                             const float* __restrict__ w_dt,
                                             const float* __restrict__ b_dt,
                                             float* __restrict__ bcd,
                                             float* __restrict__ dt) {
  __shared__ __align__(16) float xs[4][384];
  int wv = threadIdx.x >> 6, lane = threadIdx.x & 63;
  int tok = blockIdx.x * 4 + wv;
  const float* xr = xa + (size_t)tok * DI_;
  for (int f = lane; f < 384; f += 64) xs[wv][f] = xr[f];
  float a = 0.f;
  if (lane < 33) {
    const float* wrow = w_x + lane * 384;
#pragma unroll 4
    for (int k = 0; k < 384; k += 4) {
      float4 xv = *(const float4*)(&xs[wv][k]);
      float4 ww = *(const float4*)(wrow + k);
      a = fmaf(xv.x, ww.x, a);
      a = fmaf(xv.y, ww.y, a);
      a = fmaf(xv.z, ww.z, a);
      a = fmaf(xv.w, ww.w, a);
    }
    bcd[(size_t)tok * 33 + lane] = a;
  }
  float dtraw = __shfl(a, 32, 64);
#pragma unroll
  for (int j = 0; j < 6; j++) {
    int d = lane + j * 64;
    float v = fmaf(dtraw, w_dt[d], b_dt[d]);
    dt[(size_t)tok * DI_ + d] = (v > 20.f) ? v : log1pf(expf(v));
  }
}

// ---------------- selective scan: block = 16 d x 16 n ; serial over L ----------------
__global__ __launch_bounds__(256) void k_scan(const float* __restrict__ bcd,
                                              const float* __restrict__ dt,
                                              const float* __restrict__ xa,
                                              const float* __restrict__ sz,
                                              const float* __restrict__ A_log,
                                              const float* __restrict__ D_ssm,
                                              float* __restrict__ y) {
  int b = blockIdx.x / 24, chunk = blockIdx.x % 24;
  int tid = threadIdx.x;
  int dl = tid >> 4, n = tid & 15;
  int d = chunk * 16 + dl;
  float Av = -expf(A_log[d * 16 + n]);
  float Dv = D_ssm[d];
  const float* bcd_b = bcd + (size_t)b * L_ * 33;
  const float* dt_b = dt + (size_t)b * L_ * DI_ + d;
  const float* xa_b = xa + (size_t)b * L_ * DI_ + d;
  const float* sz_b = sz + (size_t)b * L_ * DI_ + d;
  float* y_b = y + (size_t)b * L_ * DI_ + d;
  float h = 0.f;
  for (int l0 = 0; l0 < L_; l0 += 8) {
    float Bn[8], Cn[8], dtv[8], xv[8], szv[8];
#pragma unroll
    for (int j = 0; j < 8; j++) {
      int l = l0 + j;
      if (l < L_) {
        Bn[j] = bcd_b[l * 33 + n];
        Cn[j] = bcd_b[l * 33 + 16 + n];
        dtv[j] = dt_b[(size_t)l * DI_];
        xv[j] = xa_b[(size_t)l * DI_];
        if (n == 0) szv[j] = sz_b[(size_t)l * DI_];
      }
    }
#pragma unroll
    for (int j = 0; j < 8; j++) {
      int l = l0 + j;
      if (l < L_) {
        float dA = expf(dtv[j] * Av);
        h = fmaf(dA, h, dtv[j] * Bn[j] * xv[j]);
        float c = h * Cn[j];
        c += __shfl_xor(c, 1, 16);
        c += __shfl_xor(c, 2, 16);
        c += __shfl_xor(c, 4, 16);
        c += __shfl_xor(c, 8, 16);
        if (n == 0) y_b[(size_t)l * DI_] = fmaf(xv[j], Dv, c) * szv[j];
      }
    }
  }
}

// ---------------- t += y @ w_out^T : tiles of 16 tokens, 4m x 3n reg tile ----------------
__global__ __launch_bounds__(256) void k_gemm_out(const float* __restrict__ a,
                                                  const float* __restrict__ w,
                                                  float* __restrict__ t) {
  __shared__ __align__(16) float a_s[16 * 388];
  int tile = blockIdx.x, tid = threadIdx.x;
  const float* ar = a + (size_t)tile * 16 * 384;
#pragma unroll
  for (int jj = 0; jj < 6; jj++) {
    int idx = tid + jj * 256;       // f4 index 0..1535 (96 per token)
    int m = idx / 96;
    int q = idx - m * 96;
    float4 v = *(const float4*)(ar + m * 384 + q * 4);
    *(float4*)(a_s + m * 388 + q * 4) = v;
  }
  __syncthreads();
  int mg = tid >> 6;
  int ng = tid & 63;
  float acc[4][3];
#pragma unroll
  for (int i = 0; i < 4; i++)
#pragma unroll
    for (int j = 0; j < 3; j++) acc[i][j] = 0.f;
  const float* w0 = w + (size_t)ng * 384;
  const float* w1 = w + (size_t)(ng + 64) * 384;
  const float* w2 = w + (size_t)(ng + 128) * 384;
  const float* a0 = a_s + (mg * 4 + 0) * 388;
  const float* a1 = a_s + (mg * 4 + 1) * 388;
  const float* a2 = a_s + (mg * 4 + 2) * 388;
  const float* a3 = a_s + (mg * 4 + 3) * 388;
  for (int k = 0; k < 384; k += 4) {
    float4 wv0 = *(const float4*)(w0 + k);
    float4 wv1 = *(const float4*)(w1 + k);
    float4 wv2 = *(const float4*)(w2 + k);
    float4 av0 = *(const float4*)(a0 + k);
    float4 av1 = *(const float4*)(a1 + k);
    float4 av2 = *(const float4*)(a2 + k);
    float4 av3 = *(const float4*)(a3 + k);
    FMA4(acc[0][0], av0, wv0); FMA4(acc[0][1], av0, wv1); FMA4(acc[0][2], av0, wv2);
    FMA4(acc[1][0], av1, wv0); FMA4(acc[1][1], av1, wv1); FMA4(acc[1][2], av1, wv2);
    FMA4(acc[2][0], av2, wv0); FMA4(acc[2][1], av2, wv1); FMA4(acc[2][2], av2, wv2);
    FMA4(acc[3][0], av3, wv0); FMA4(acc[3][1], av3, wv1); FMA4(acc[3][2], av3, wv2);
  }
#pragma unroll
  for (int i = 0; i < 4; i++) {
    size_t row = (size_t)tile * 16 + mg * 4 + i;
#pragma unroll
    for (int j = 0; j < 3; j++) {
      size_t idx = row * 192 + ng + 64 * j;
      t[idx] += acc[i][j];
    }
  }
}

// ---------------- final LN(token 0) + cls head + reg head ----------------
__global__ __launch_bounds__(192) void k_head(const float* __restrict__ t,
                                              const float* __restrict__ fn_g,
                                              const float* __restrict__ fn_b,
                                              const float* __restrict__ cls_w,
                                              const float* __restrict__ cls_b,
                                              const float* __restrict__ rw1,
                                              const float* __restrict__ rb1,
                                              const float* __restrict__ rw2,
                                              const float* __restrict__ rb2,
                                              float* __restrict__ out) {
  __shared__ float red[8];
  __shared__ float stats[2];
  __shared__ float feat_s[192];
  __shared__ float h_s[96];
  int b = blockIdx.x, tid = threadIdx.x;
  float x = t[(size_t)b * L_ * D_ + tid];
  float s = x, q = x * x;
#pragma unroll
  for (int off = 1; off < 64; off <<= 1) {
    s += __shfl_xor(s, off, 64);
    q += __shfl_xor(q, off, 64);
  }
  int w = tid >> 6;
  if ((tid & 63) == 0) { red[w] = s; red[4 + w] = q; }
  __syncthreads();
  if (tid == 0) {
    float ss = red[0] + red[1] + red[2];
    float qq = red[4] + red[5] + red[6];
    float m = ss * (1.f / 192.f);
    stats[0] = m;
    stats[1] = rsqrtf(qq * (1.f / 192.f) - m * m + 1e-5f);
  }
  __syncthreads();
  float fv = (x - stats[0]) * stats[1] * fn_g[tid] + fn_b[tid];
  feat_s[tid] = fv;
  __syncthreads();
  if (tid < 96) {
    float a = rb1[tid];
    const float* wr = rw1 + (size_t)tid * 192;
    for (int k = 0; k < 192; k++) a = fmaf(feat_s[k], wr[k], a);
    h_s[tid] = 0.5f * a * (1.f + erff(a * 0.70710678118654752f));
  } else if (tid < 98) {
    int c = tid - 96;
    float a = cls_b[c];
    const float* wr = cls_w + (size_t)c * 192;
    for (int k = 0; k < 192; k++) a = fmaf(feat_s[k], wr[k], a);
    out[b * 2 + c] = a;
  }
  __syncthreads();
  if (tid == 0) {
    float a = rb2[0];
    for (int j = 0; j < 96; j++) a = fmaf(h_s[j], rw2[j], a);
    out[64 + b] = a;
  }
}

extern "C" void kernel_launch(void* const* d_in, const int* in_sizes, int n_in,
                              void* d_out, int out_size, void* d_ws, size_t ws_size,
                              hipStream_t stream) {
  const float* x       = (const float*)d_in[0];
  const float* patch_w = (const float*)d_in[1];
  const float* patch_b = (const float*)d_in[2];
  const float* cls_tok = (const float*)d_in[3];
  const float* pos     = (const float*)d_in[4];
  const float* ln_g    = (const float*)d_in[5];
  const float* ln_b    = (const float*)d_in[6];
  const float* w_in    = (const float*)d_in[7];
  const float* conv_w  = (const float*)d_in[8];
  const float* conv_b  = (const float*)d_in[9];
  const float* w_x     = (const float*)d_in[10];
  const float* w_dt    = (const float*)d_in[11];
  const float* b_dt    = (const float*)d_in[12];
  const float* A_log   = (const float*)d_in[13];
  const float* D_ssm   = (const float*)d_in[14];
  const float* w_out   = (const float*)d_in[15];
  const float* fn_g    = (const float*)d_in[16];
  const float* fn_b    = (const float*)d_in[17];
  const float* cls_w   = (const float*)d_in[18];
  const float* cls_b   = (const float*)d_in[19];
  const float* reg_w1  = (const float*)d_in[20];
  const float* reg_b1  = (const float*)d_in[21];
  const float* reg_w2  = (const float*)d_in[22];
  const float* reg_b2  = (const float*)d_in[23];
  float* out = (float*)d_out;

  float* ws = (float*)d_ws;
  // workspace layout (floats)
  float* t_buf = ws;                       // B*L*D   = 1210368
  float* xz    = t_buf + 1210368;          // B*L*768 = 4841472
  float* xa    = xz + 4841472;             // B*L*384 = 2420736
  float* szb   = xa + 2420736;             // B*L*384
  float* bcd   = szb + 2420736;            // B*L*33  = 208032
  float* dtb   = bcd + 208032;             // B*L*384
  float* yb    = dtb + 2420736;            // B*L*384

  k_cls<<<32, 192, 0, stream>>>(cls_tok, pos, t_buf);
  k_patch<<<392, 256, 0, stream>>>(x, patch_w, patch_b, pos, t_buf);
  for (int i = 0; i < DEPTH_; i++) {
    k_ln_gemm_in<<<788, 256, 0, stream>>>(t_buf, ln_g + i * D_, ln_b + i * D_,
                                          w_in + (size_t)i * 768 * D_, xz);
    k_conv<<<B_ * L_, 384, 0, stream>>>(xz, conv_w + i * DI_ * DC_, conv_b + i * DI_, xa, szb);
    k_bcd<<<1576, 256, 0, stream>>>(xa, w_x + i * 33 * DI_, w_dt + i * DI_, b_dt + i * DI_, bcd, dtb);
    k_scan<<<768, 256, 0, stream>>>(bcd, dtb, xa, szb, A_log + i * DI_ * DS_, D_ssm + i * DI_, yb);
    k_gemm_out<<<394, 256, 0, stream>>>(yb, w_out + (size_t)i * D_ * DI_, t_buf);
  }
  k_head<<<32, 192, 0, stream>>>(t_buf, fn_g, fn_b, cls_w, cls_b, reg_w1, reg_b1,
                                 reg_w2, reg_b2, out);
}

// Round 3
// 744.865 us; speedup vs baseline: 2.8916x; 2.8916x over previous
//
#include <hip/hip_runtime.h>
#include <hip/hip_bf16.h>
#include <math.h>

// Problem constants
#define B_ 32
#define D_ 192
#define DEPTH_ 4
#define DI_ 384
#define DS_ 16
#define DC_ 4
#define P_ 16
#define IMG_ 224
#define N_ 196
#define L_ 197

typedef short s16x8 __attribute__((ext_vector_type(8)));
typedef float f32x16 __attribute__((ext_vector_type(16)));

__device__ __forceinline__ float sigmoidf_(float x) { return 1.f / (1.f + expf(-x)); }

// ---------------- weight cast fp32 -> bf16 ----------------
__global__ void k_cast(const float* __restrict__ s, __hip_bfloat16* __restrict__ d, int n) {
  for (int i = blockIdx.x * 256 + threadIdx.x; i < n; i += gridDim.x * 256)
    d[i] = __float2bfloat16(s[i]);
}

// ---------------- cls token + pos embed (row l=0) ----------------
__global__ void k_cls(const float* __restrict__ cls_tok, const float* __restrict__ pos,
                      float* __restrict__ t) {
  int b = blockIdx.x, d = threadIdx.x;
  t[(size_t)b * L_ * D_ + d] = cls_tok[d] + pos[d];
}

// ---------------- im2col: x (B,3,224,224) -> A bf16 (6272 x 768) ----------------
__global__ __launch_bounds__(256) void k_im2col(const float* __restrict__ x,
                                                __hip_bfloat16* __restrict__ A) {
  int idx = blockIdx.x * 256 + threadIdx.x;  // grid exact: 18816*256 = 6272*768
  int tok = idx / 768, f = idx - tok * 768;
  int b = tok / 196, p = tok - b * 196;
  int h = p / 14, w = p - h * 14;
  int c = f >> 8, i = (f >> 4) & 15, j = f & 15;
  float v = x[(((size_t)(b * 3 + c) * 224 + h * 16 + i) * 224 + w * 16 + j)];
  A[idx] = __float2bfloat16(v);
}

// ---------------- generic bf16 MFMA GEMM: C[M x N] = A[M x K] @ W[N x K]^T ----------------
// block = 256 thr (4 waves), tile M64 x N64, wave tile 32x32 (mfma_f32_32x32x16_bf16)
// K-chunks of 96 staged in LDS (both operands), stride 104 to tame bank conflicts.
// MODE 0: C (stride 768) = acc                       (xz = ln(t) @ w_in^T)
// MODE 1: C (stride 192) += acc                      (t += y @ w_out^T)
// MODE 2: patch epilogue: t[(b*197+1+p)*192+n] = acc + bias[n] + pos[(1+p)*192+n]
template <int KTOT, int MODE>
__global__ __launch_bounds__(256) void k_gemm_mfma(const short* __restrict__ A,
                                                   const short* __restrict__ Wb,
                                                   float* __restrict__ C,
                                                   const float* __restrict__ bias,
                                                   const float* __restrict__ pos,
                                                   int M) {
  constexpr int KC = 96;
  constexpr int STR = 104;  // 208 B row stride -> 4-way bank conflict worst case (1.58x)
  __shared__ __align__(16) short Als[64 * STR];
  __shared__ __align__(16) short Bls[64 * STR];
  int m0 = blockIdx.x * 64, n0 = blockIdx.y * 64;
  int tid = threadIdx.x;
  int lane = tid & 63, wid = tid >> 6;
  int mw = (wid & 1) * 32, nw = (wid >> 1) * 32;
  int l31 = lane & 31, lh = lane >> 5;
  f32x16 acc;
#pragma unroll
  for (int i = 0; i < 16; i++) acc[i] = 0.f;
  for (int kc = 0; kc < KTOT; kc += KC) {
    __syncthreads();
#pragma unroll
    for (int i = 0; i < 3; i++) {
      int seg = tid + i * 256;        // 768 segments: 64 rows x 12 k-segs of 8 bf16
      int r = seg / 12, s = seg - r * 12;
      *(s16x8*)(Als + r * STR + s * 8) =
          *(const s16x8*)(A + (size_t)(m0 + r) * KTOT + kc + s * 8);
      *(s16x8*)(Bls + r * STR + s * 8) =
          *(const s16x8*)(Wb + (size_t)(n0 + r) * KTOT + kc + s * 8);
    }
    __syncthreads();
#pragma unroll
    for (int ks = 0; ks < KC / 16; ks++) {
      s16x8 af = *(const s16x8*)(Als + (mw + l31) * STR + ks * 16 + lh * 8);
      s16x8 bf = *(const s16x8*)(Bls + (nw + l31) * STR + ks * 16 + lh * 8);
      acc = __builtin_amdgcn_mfma_f32_32x32x16_bf16(af, bf, acc, 0, 0, 0);
    }
  }
  // epilogue: C/D layout col=lane&31, row=(reg&3)+8*(reg>>2)+4*(lane>>5)
  int gn = n0 + nw + l31;
#pragma unroll
  for (int i = 0; i < 16; i++) {
    int rowt = mw + (i & 3) + 8 * (i >> 2) + 4 * lh;
    int gm = m0 + rowt;
    float v = acc[i];
    if (MODE == 0) {
      if (gm < M) C[(size_t)gm * 768 + gn] = v;
    } else if (MODE == 1) {
      if (gm < M) C[(size_t)gm * 192 + gn] += v;
    } else {
      int b = gm / 196, p = gm - b * 196;
      C[((size_t)b * 197 + 1 + p) * 192 + gn] =
          v + bias[gn] + pos[(size_t)(1 + p) * 192 + gn];
    }
  }
}

// ---------------- LayerNorm per token -> bf16 out ----------------
__global__ __launch_bounds__(64) void k_ln_bf(const float* __restrict__ t,
                                              const float* __restrict__ g,
                                              const float* __restrict__ bb,
                                              __hip_bfloat16* __restrict__ o) {
  int tok = blockIdx.x, tid = threadIdx.x;
  const float* xr = t + (size_t)tok * D_;
  float x0 = xr[tid], x1 = xr[tid + 64], x2 = xr[tid + 128];
  float s = x0 + x1 + x2;
  float q = x0 * x0 + x1 * x1 + x2 * x2;
#pragma unroll
  for (int off = 1; off < 64; off <<= 1) {
    s += __shfl_xor(s, off, 64);
    q += __shfl_xor(q, off, 64);
  }
  float m = s * (1.f / 192.f);
  float r = rsqrtf(q * (1.f / 192.f) - m * m + 1e-5f);
  __hip_bfloat16* orow = o + (size_t)tok * D_;
  orow[tid]       = __float2bfloat16((x0 - m) * r * g[tid] + bb[tid]);
  orow[tid + 64]  = __float2bfloat16((x1 - m) * r * g[tid + 64] + bb[tid + 64]);
  orow[tid + 128] = __float2bfloat16((x2 - m) * r * g[tid + 128] + bb[tid + 128]);
}

// ---------------- causal depthwise conv (DC=4) + silu -> xa ; silu(z) -> sz ----------------
__global__ __launch_bounds__(384) void k_conv(const float* __restrict__ xz,
                                              const float* __restrict__ cw_,
                                              const float* __restrict__ cb,
                                              float* __restrict__ xa,
                                              float* __restrict__ sz) {
  int row = blockIdx.x;  // b*L + l
  int l = row % L_;
  int d = threadIdx.x;
  float4 cw = *(const float4*)(cw_ + d * 4);
  const float* xc = xz + (size_t)row * 768 + d;
  float acc = cb[d];
  acc = fmaf(cw.w, xc[0], acc);
  if (l >= 1) acc = fmaf(cw.z, xc[-768], acc);
  if (l >= 2) acc = fmaf(cw.y, xc[-2 * 768], acc);
  if (l >= 3) acc = fmaf(cw.x, xc[-3 * 768], acc);
  xa[(size_t)row * DI_ + d] = acc * sigmoidf_(acc);
  float z = xc[384];
  sz[(size_t)row * DI_ + d] = z * sigmoidf_(z);
}

// ---------------- bcd = xa @ w_x^T (N=33) ; fused dt = softplus(bcd[32]*w_dt+b_dt) ----------------
__global__ __launch_bounds__(256) void k_bcd(const float* __restrict__ xa,
                                             const float* __restrict__ w_x,
                                             const float* __restrict__ w_dt,
                                             const float* __restrict__ b_dt,
                                             float* __restrict__ bcd,
                                             float* __restrict__ dt) {
  __shared__ __align__(16) float xs[4][384];
  int wv = threadIdx.x >> 6, lane = threadIdx.x & 63;
  int tok = blockIdx.x * 4 + wv;
  const float* xr = xa + (size_t)tok * DI_;
  for (int f = lane; f < 384; f += 64) xs[wv][f] = xr[f];
  float a = 0.f;
  if (lane < 33) {
    const float* wrow = w_x + lane * 384;
#pragma unroll 4
    for (int k = 0; k < 384; k += 4) {
      float4 xv = *(const float4*)(&xs[wv][k]);
      float4 ww = *(const float4*)(wrow + k);
      a = fmaf(xv.x, ww.x, a);
      a = fmaf(xv.y, ww.y, a);
      a = fmaf(xv.z, ww.z, a);
      a = fmaf(xv.w, ww.w, a);
    }
    bcd[(size_t)tok * 33 + lane] = a;
  }
  float dtraw = __shfl(a, 32, 64);
#pragma unroll
  for (int j = 0; j < 6; j++) {
    int d = lane + j * 64;
    float v = fmaf(dtraw, w_dt[d], b_dt[d]);
    dt[(size_t)tok * DI_ + d] = (v > 20.f) ? v : log1pf(expf(v));
  }
}

// ---------------- selective scan: block = 16 d x 16 n ; serial over L; y out bf16 ----------------
__global__ __launch_bounds__(256) void k_scan(const float* __restrict__ bcd,
                                              const float* __restrict__ dt,
                                              const float* __restrict__ xa,
                                              const float* __restrict__ sz,
                                              const float* __restrict__ A_log,
                                              const float* __restrict__ D_ssm,
                                              __hip_bfloat16* __restrict__ y) {
  int b = blockIdx.x / 24, chunk = blockIdx.x % 24;
  int tid = threadIdx.x;
  int dl = tid >> 4, n = tid & 15;
  int d = chunk * 16 + dl;
  float Av = -expf(A_log[d * 16 + n]);
  float Dv = D_ssm[d];
  const float* bcd_b = bcd + (size_t)b * L_ * 33;
  const float* dt_b = dt + (size_t)b * L_ * DI_ + d;
  const float* xa_b = xa + (size_t)b * L_ * DI_ + d;
  const float* sz_b = sz + (size_t)b * L_ * DI_ + d;
  __hip_bfloat16* y_b = y + (size_t)b * L_ * DI_ + d;
  float h = 0.f;
  for (int l0 = 0; l0 < L_; l0 += 8) {
    float Bn[8], Cn[8], dtv[8], xv[8], szv[8];
#pragma unroll
    for (int j = 0; j < 8; j++) {
      int l = l0 + j;
      if (l < L_) {
        Bn[j] = bcd_b[l * 33 + n];
        Cn[j] = bcd_b[l * 33 + 16 + n];
        dtv[j] = dt_b[(size_t)l * DI_];
        xv[j] = xa_b[(size_t)l * DI_];
        if (n == 0) szv[j] = sz_b[(size_t)l * DI_];
      }
    }
#pragma unroll
    for (int j = 0; j < 8; j++) {
      int l = l0 + j;
      if (l < L_) {
        float dA = expf(dtv[j] * Av);
        h = fmaf(dA, h, dtv[j] * Bn[j] * xv[j]);
        float c = h * Cn[j];
        c += __shfl_xor(c, 1, 16);
        c += __shfl_xor(c, 2, 16);
        c += __shfl_xor(c, 4, 16);
        c += __shfl_xor(c, 8, 16);
        if (n == 0) y_b[(size_t)l * DI_] = __float2bfloat16(fmaf(xv[j], Dv, c) * szv[j]);
      }
    }
  }
}

// ---------------- final LN(token 0) + cls head + reg head ----------------
__global__ __launch_bounds__(192) void k_head(const float* __restrict__ t,
                                              const float* __restrict__ fn_g,
                                              const float* __restrict__ fn_b,
                                              const float* __restrict__ cls_w,
                                              const float* __restrict__ cls_b,
                                              const float* __restrict__ rw1,
                                              const float* __restrict__ rb1,
                                              const float* __restrict__ rw2,
                                              const float* __restrict__ rb2,
                                              float* __restrict__ out) {
  __shared__ float red[8];
  __shared__ float stats[2];
  __shared__ float feat_s[192];
  __shared__ float h_s[96];
  int b = blockIdx.x, tid = threadIdx.x;
  float x = t[(size_t)b * L_ * D_ + tid];
  float s = x, q = x * x;
#pragma unroll
  for (int off = 1; off < 64; off <<= 1) {
    s += __shfl_xor(s, off, 64);
    q += __shfl_xor(q, off, 64);
  }
  int w = tid >> 6;
  if ((tid & 63) == 0) { red[w] = s; red[4 + w] = q; }
  __syncthreads();
  if (tid == 0) {
    float ss = red[0] + red[1] + red[2];
    float qq = red[4] + red[5] + red[6];
    float m = ss * (1.f / 192.f);
    stats[0] = m;
    stats[1] = rsqrtf(qq * (1.f / 192.f) - m * m + 1e-5f);
  }
  __syncthreads();
  float fv = (x - stats[0]) * stats[1] * fn_g[tid] + fn_b[tid];
  feat_s[tid] = fv;
  __syncthreads();
  if (tid < 96) {
    float a = rb1[tid];
    const float* wr = rw1 + (size_t)tid * 192;
    for (int k = 0; k < 192; k++) a = fmaf(feat_s[k], wr[k], a);
    h_s[tid] = 0.5f * a * (1.f + erff(a * 0.70710678118654752f));
  } else if (tid < 98) {
    int c = tid - 96;
    float a = cls_b[c];
    const float* wr = cls_w + (size_t)c * 192;
    for (int k = 0; k < 192; k++) a = fmaf(feat_s[k], wr[k], a);
    out[b * 2 + c] = a;
  }
  __syncthreads();
  if (tid == 0) {
    float a = rb2[0];
    for (int j = 0; j < 96; j++) a = fmaf(h_s[j], rw2[j], a);
    out[64 + b] = a;
  }
}

extern "C" void kernel_launch(void* const* d_in, const int* in_sizes, int n_in,
                              void* d_out, int out_size, void* d_ws, size_t ws_size,
                              hipStream_t stream) {
  const float* x       = (const float*)d_in[0];
  const float* patch_w = (const float*)d_in[1];
  const float* patch_b = (const float*)d_in[2];
  const float* cls_tok = (const float*)d_in[3];
  const float* pos     = (const float*)d_in[4];
  const float* ln_g    = (const float*)d_in[5];
  const float* ln_b    = (const float*)d_in[6];
  const float* w_in    = (const float*)d_in[7];
  const float* conv_w  = (const float*)d_in[8];
  const float* conv_b  = (const float*)d_in[9];
  const float* w_x     = (const float*)d_in[10];
  const float* w_dt    = (const float*)d_in[11];
  const float* b_dt    = (const float*)d_in[12];
  const float* A_log   = (const float*)d_in[13];
  const float* D_ssm   = (const float*)d_in[14];
  const float* w_out   = (const float*)d_in[15];
  const float* fn_g    = (const float*)d_in[16];
  const float* fn_b    = (const float*)d_in[17];
  const float* cls_w   = (const float*)d_in[18];
  const float* cls_b   = (const float*)d_in[19];
  const float* reg_w1  = (const float*)d_in[20];
  const float* reg_b1  = (const float*)d_in[21];
  const float* reg_w2  = (const float*)d_in[22];
  const float* reg_b2  = (const float*)d_in[23];
  float* out = (float*)d_out;

  float* ws = (float*)d_ws;
  // workspace layout (floats); M padded to 6336 for bf16 activation buffers
  float* t_buf = ws;                        // 32*197*192 = 1,210,368
  float* xz    = t_buf + 1210368;           // 6304*768   = 4,841,472
  float* xa    = xz + 4841472;              // 6304*384   = 2,420,736
  float* szb   = xa + 2420736;              // 2,420,736
  float* bcd   = szb + 2420736;             // 6304*33    = 208,032
  float* dtb   = bcd + 208032;              // 2,420,736  (aliased by Abuf below)
  __hip_bfloat16* Abuf = (__hip_bfloat16*)dtb;  // 6272*768 bf16 (used only before layer loop)
  __hip_bfloat16* xln_bf = (__hip_bfloat16*)(dtb + 2420736);  // 6336*192 bf16 = 1,216,512
  __hip_bfloat16* y_bf   = xln_bf + 1216512;                  // 6336*384 bf16 = 2,433,024
  __hip_bfloat16* pw_bf  = y_bf + 2433024;                    // 147,456
  __hip_bfloat16* win_bf = pw_bf + 147456;                    // 589,824
  __hip_bfloat16* wout_bf = win_bf + 589824;                  // 294,912

  // weight casts (every call; same work each time)
  k_cast<<<256, 256, 0, stream>>>(patch_w, pw_bf, 147456);
  k_cast<<<256, 256, 0, stream>>>(w_in, win_bf, 589824);
  k_cast<<<256, 256, 0, stream>>>(w_out, wout_bf, 294912);

  k_cls<<<32, 192, 0, stream>>>(cls_tok, pos, t_buf);
  k_im2col<<<18816, 256, 0, stream>>>(x, Abuf);
  k_gemm_mfma<768, 2><<<dim3(98, 3), 256, 0, stream>>>(
      (const short*)Abuf, (const short*)pw_bf, t_buf, patch_b, pos, 6272);

  for (int i = 0; i < DEPTH_; i++) {
    k_ln_bf<<<B_ * L_, 64, 0, stream>>>(t_buf, ln_g + i * D_, ln_b + i * D_, xln_bf);
    k_gemm_mfma<192, 0><<<dim3(99, 12), 256, 0, stream>>>(
        (const short*)xln_bf, (const short*)(win_bf + (size_t)i * 147456), xz,
        nullptr, nullptr, 6304);
    k_conv<<<B_ * L_, 384, 0, stream>>>(xz, conv_w + i * DI_ * DC_, conv_b + i * DI_, xa, szb);
    k_bcd<<<1576, 256, 0, stream>>>(xa, w_x + i * 33 * DI_, w_dt + i * DI_, b_dt + i * DI_,
                                    bcd, dtb);
    k_scan<<<768, 256, 0, stream>>>(bcd, dtb, xa, szb, A_log + i * DI_ * DS_, D_ssm + i * DI_,
                                    y_bf);
    k_gemm_mfma<384, 1><<<dim3(99, 3), 256, 0, stream>>>(
        (const short*)y_bf, (const short*)(wout_bf + (size_t)i * 73728), t_buf,
        nullptr, nullptr, 6304);
  }
  k_head<<<32, 192, 0, stream>>>(t_buf, fn_g, fn_b, cls_w, cls_b, reg_w1, reg_b1,
                                 reg_w2, reg_b2, out);
}